// Round 4
// baseline (100.416 us; speedup 1.0000x reference)
//
#include <hip/hip_runtime.h>
#include <math.h>

#define NS 256000
#define N1 512            // FFT over n1: radix 8,8,8
#define N2 500            // FFT over n2: radices 5,5,5,4
#define YS 528            // padded Y row stride (cplx) — breaks 4KB L2-set aliasing
#define PI_F 3.14159265358979323846f

typedef float2 cplx;

__device__ __forceinline__ cplx cadd(cplx a, cplx b){ return make_float2(a.x+b.x, a.y+b.y); }
__device__ __forceinline__ cplx csub(cplx a, cplx b){ return make_float2(a.x-b.x, a.y-b.y); }
__device__ __forceinline__ cplx cmul(cplx a, cplx b){ return make_float2(a.x*b.x-a.y*b.y, a.x*b.y+a.y*b.x); }
__device__ __forceinline__ cplx cmulc(cplx a, cplx b){ return make_float2(a.x*b.x+a.y*b.y, a.y*b.x-a.x*b.y); }
__device__ __forceinline__ cplx crotf(cplx v, float ang){
    float sn = __sinf(ang), cs = __cosf(ang);
    return make_float2(v.x*cs - v.y*sn, v.x*sn + v.y*cs);
}
// padded LDS index: +1 word every 16 elements -> <=2-way bank aliasing
__device__ __forceinline__ int PX(int e){ return e + (e>>4); }
// octal digit reversal of 9 bits (involution)
__device__ __forceinline__ int rev8_3(int k){ return ((k&7)<<6) | (k&0x38) | (k>>6); }

#define U1PAD 545   // >= PX(511)+1 = 543
#define U2PAD 537   // >= PX(499)+1 = 531
// wave-level LDS fence: wave-private columns, no block barrier needed
#define WFENCE() asm volatile("s_waitcnt lgkmcnt(0)" ::: "memory")
// LDS-only block barrier: does NOT drain vmcnt, so global loads stay in flight
#define LDS_BARRIER() do{ asm volatile("s_waitcnt lgkmcnt(0)" ::: "memory"); __builtin_amdgcn_s_barrier(); }while(0)

template<bool INV>
__device__ __forceinline__ void dft4(const cplx* a, cplx* b){
    cplx t0=cadd(a[0],a[2]), t1=csub(a[0],a[2]), t2=cadd(a[1],a[3]), t3=csub(a[1],a[3]);
    b[0]=cadd(t0,t2); b[2]=csub(t0,t2);
    if(!INV){ b[1]=make_float2(t1.x+t3.y, t1.y-t3.x); b[3]=make_float2(t1.x-t3.y, t1.y+t3.x); }
    else    { b[1]=make_float2(t1.x-t3.y, t1.y+t3.x); b[3]=make_float2(t1.x+t3.y, t1.y-t3.x); }
}

template<bool INV>
__device__ __forceinline__ void dft8(const cplx* a, cplx* b){
    cplx ev[4]={a[0],a[2],a[4],a[6]}, od[4]={a[1],a[3],a[5],a[7]};
    cplx C[4], D[4];
    dft4<INV>(ev, C); dft4<INV>(od, D);
    const float s = 0.70710678118654752f;
    const float sg = INV ? 1.f : -1.f;
    cplx d1 = cmul(D[1], make_float2( s, sg*s));
    cplx d2 = cmul(D[2], make_float2(0.f, sg ));
    cplx d3 = cmul(D[3], make_float2(-s, sg*s));
    b[0]=cadd(C[0],D[0]); b[4]=csub(C[0],D[0]);
    b[1]=cadd(C[1],d1);   b[5]=csub(C[1],d1);
    b[2]=cadd(C[2],d2);   b[6]=csub(C[2],d2);
    b[3]=cadd(C[3],d3);   b[7]=csub(C[3],d3);
}

template<bool INV>
__device__ __forceinline__ void dft5(const cplx* a, cplx* b){
    const float c1=0.30901699437494742f, s1=0.95105651629515357f;
    const float c2=-0.80901699437494745f, s2=0.58778525229247312f;
    const float sg = INV ? 1.f : -1.f;
    cplx W[5];
    W[0]=make_float2(1.f,0.f);
    W[1]=make_float2(c1, sg*s1); W[2]=make_float2(c2, sg*s2);
    W[3]=make_float2(c2,-sg*s2); W[4]=make_float2(c1,-sg*s1);
#pragma unroll
    for(int u=0;u<5;++u){
        cplx acc = a[0];
        int idx = 0;
#pragma unroll
        for(int r=1;r<5;++r){
            idx += u; if(idx >= 5) idx -= 5;
            acc = cadd(acc, cmul(a[r], W[idx]));
        }
        b[u] = acc;
    }
}

// Rolled wave-private 512-pt FFT: one loop body for all 3 radix-8 stages.
// fwd: sh = 6,3,0 (DIF); inv: sh = 0,3,6 (DIT). tsh = 6 - sh. All bit ops.
template<bool INV>
__device__ __forceinline__ void fft512_wave(cplx* Uw, const cplx* tab, int lane){
#pragma unroll 1
    for(int st=0; st<3; ++st){
        const int sh = INV ? 3*st : 6-3*st;
        const int m = 1<<sh;
        const int blk = lane >> sh, j = lane & (m-1);
        const int base = (blk << (sh+3)) + j;
        cplx a[8], wt[8];
#pragma unroll
        for(int t=0;t<8;++t) a[t] = Uw[PX(base + (t<<sh))];
#pragma unroll
        for(int t=1;t<8;++t) wt[t] = tab[(j*t) << (6-sh)];
        if(INV){
#pragma unroll
            for(int t=1;t<8;++t) a[t] = cmulc(a[t], wt[t]);
        }
        cplx bb[8];
        dft8<INV>(a,bb);
        if(!INV){
#pragma unroll
            for(int t=1;t<8;++t) bb[t] = cmul(bb[t], wt[t]);
        }
#pragma unroll
        for(int t=0;t<8;++t) Uw[PX(base + (t<<sh))] = bb[t];
        WFENCE();
    }
}

// Rolled wave-private 500-pt FFT: one body for the 3 radix-5 stages
// (m = 100,20,4; TMUL = 1,5,25) + tiny radix-4 stage (m=1, twiddle==1).
// Exact magic-div: beta/20 = (beta*52429)>>20 (exact for beta<100).
template<bool INV>
__device__ __forceinline__ void fft500_wave(cplx* Uw, const cplx* tab, int lane){
    if(INV){
#pragma unroll 1
        for(int it=0; it<2; ++it){
            int beta = lane + 64*it;
            if(beta < 125){
                int base = beta*4;
                cplx a[4];
#pragma unroll
                for(int t=0;t<4;++t) a[t] = Uw[PX(base+t)];
                cplx bb[4];
                dft4<true>(a,bb);
#pragma unroll
                for(int t=0;t<4;++t) Uw[PX(base+t)] = bb[t];
            }
        }
        WFENCE();
    }
#pragma unroll 1
    for(int s5=0; s5<3; ++s5){
        const int st = INV ? 2-s5 : s5;
        const int m  = (st==0)?100:((st==1)?20:4);
        const int tm = (st==0)?1:((st==1)?5:25);
#pragma unroll 1
        for(int it=0; it<2; ++it){
            int beta = lane + 64*it;
            if(beta < 100){
                int blk = (st==0) ? 0 : ((st==1) ? (int)(((unsigned)beta*52429u)>>20) : (beta>>2));
                int j = beta - blk*m;
                int base = blk*(m*5) + j;
                cplx a[5], wt[5];
#pragma unroll
                for(int t=0;t<5;++t) a[t] = Uw[PX(base + m*t)];
#pragma unroll
                for(int t=1;t<5;++t) wt[t] = tab[tm*j*t];
                if(INV){
#pragma unroll
                    for(int t=1;t<5;++t) a[t] = cmulc(a[t], wt[t]);
                }
                cplx bb[5];
                dft5<INV>(a,bb);
                if(!INV){
#pragma unroll
                    for(int t=1;t<5;++t) bb[t] = cmul(bb[t], wt[t]);
                }
#pragma unroll
                for(int t=0;t<5;++t) Uw[PX(base + m*t)] = bb[t];
            }
        }
        WFENCE();
    }
    if(!INV){
#pragma unroll 1
        for(int it=0; it<2; ++it){
            int beta = lane + 64*it;
            if(beta < 125){
                int base = beta*4;
                cplx a[4];
#pragma unroll
                for(int t=0;t<4;++t) a[t] = Uw[PX(base+t)];
                cplx bb[4];
                dft4<false>(a,bb);
#pragma unroll
                for(int t=0;t<4;++t) Uw[PX(base+t)] = bb[t];
            }
        }
        WFENCE();
    }
}

template<int NTAB, int NTHR>
__device__ __forceinline__ void build_tab(cplx* tab, int tid){
    const float step = -2.f*PI_F/(float)NTAB;
    for(int i = tid; i < NTAB; i += NTHR){
        float a = step*(float)i;
        tab[i] = make_float2(__cosf(a), __sinf(a));
    }
}

// position p -> true k2 for the radix-(5,5,5,4) DIF order
__device__ __forceinline__ int p2k2(int p){
    int t1 = p/100; int r = p - 100*t1;
    int t2 = r/20;  r -= 20*t2;
    int t3 = r>>2;  int t4 = r & 3;
    return t1 + 5*t2 + 25*t3 + 125*t4;
}
// true k2 -> position p (inverse of p2k2)
__device__ __forceinline__ int k22p(int k){
    int t1 = k % 5; int k5 = k/5;
    int t2 = k5 % 5; int k25 = k5/5;
    int t3 = k25 % 5; int t4 = k25/5;
    return 100*t1 + 20*t2 + 4*t3 + t4;
}
// column-slot -> true k1.  Slots grouped so conjugate pairs (k1, 512-k1)
// share a block: blk 0 = {0, 256} (self-paired), blk j>=1 = {j, 512-j}.
__device__ __forceinline__ int colord(int q){
    int j = q>>1, w = q&1;
    if(j == 0) return w ? 256 : 0;
    return w ? 512 - j : j;
}
// bijective XCD-chunk swizzle
__device__ __forceinline__ int xcd_chunk(int bid, int n){
    int q = n>>3, r = n&7;
    int x = bid&7, idx = bid>>3;
    return (x < r ? x*(q+1) : r*(q+1) + (x-r)*q) + idx;
}

// packed conjugate-pair filter
__device__ __forceinline__ void hpair(cplx Z1, cplx Z2, float ha, float hb,
                                      cplx* zk, cplx* znk){
    float xr = 0.5f*(Z1.x + Z2.x), xi = 0.5f*(Z1.y - Z2.y);   // Xa
    float yr = 0.5f*(Z1.y + Z2.y), yi = -0.5f*(Z1.x - Z2.x);  // Xb
    *zk  = make_float2(ha*xr - hb*yi, ha*xi + hb*yr);
    *znk = make_float2(ha*xr + hb*yi, hb*yr - ha*xi);
}

// ---------------------------------------------------------------------------
// K1: blocks 0..3 = frame-mean weights; block 4 = logff; blocks 5.. = packed
// forward 512-FFT, 4 n2-columns per 4-wave block (wave-per-column, rolled).
// ---------------------------------------------------------------------------
__global__ void __launch_bounds__(256) kFused1(const float* __restrict__ fm,
                                               const float* __restrict__ noise,
                                               float* __restrict__ mmL,
                                               cplx* __restrict__ Y){
    __shared__ float Aarr[500];
    __shared__ float wfr[500];
    __shared__ float part[256];
    __shared__ cplx tab[512];
    __shared__ cplx U[4][U1PAD];
    const int bid = blockIdx.x, tid = threadIdx.x;
    if(bid < 4){
        const int b = bid;
        for(int f = tid; f < 500; f += 256){
            long long i0 = ((long long)f*255999LL + 498LL)/499LL;
            long long i1 = ((long long)(f+1)*255999LL + 498LL)/499LL;
            long long cnt = i1 - i0;
            long long sumi = (i0 + i1 - 1)*cnt/2;
            long long num = 499LL*sumi - cnt*(long long)f*255999LL;
            Aarr[f] = (float)((double)num / 255999.0);
        }
        __syncthreads();
        for(int f = tid; f < 500; f += 256){
            long long i0 = ((long long)f*255999LL + 498LL)/499LL;
            long long i1 = ((long long)(f+1)*255999LL + 498LL)/499LL;
            double w;
            if(f < 499) w = (double)(i1 - i0) - (double)Aarr[f] + (f > 0 ? (double)Aarr[f-1] : 0.0);
            else        w = (double)Aarr[498] + 1.0;
            wfr[f] = (float)(w / (double)NS);
        }
        __syncthreads();
        const int k = tid & 63, seg = tid >> 6;
        float acc = 0.f;
        for(int f = seg*125; f < seg*125 + 125; ++f)
            acc += wfr[f] * fm[(b*500 + f)*64 + k];
        part[seg*64 + k] = acc;
        __syncthreads();
        if(tid < 64) mmL[b*64 + tid] = part[tid] + part[64+tid] + part[128+tid] + part[192+tid];
        return;
    }
    if(bid == 4){
        if(tid < 64){
            double a = log10(20.0), b2 = log10(11025.0);
            double e = a + (b2 - a)*(double)tid/63.0;
            float ff = (float)pow(10.0, e);
            mmL[256 + tid] = logf(ff + 1e-7f);
        }
        return;
    }
    // ---- packed forward 512-FFT: 4 columns per block ----
    const int g = xcd_chunk(bid - 5, 250);     // [0,250)
    const int s = g / 125;                     // signal
    const int n2base = (g - s*125) * 4;
    const int lane = tid & 63, w = tid >> 6;
    build_tab<512,256>(tab, tid);
    const float* xa = noise + (size_t)(2*s)*NS + n2base;
    const float* xb = noise + (size_t)(2*s+1)*NS + n2base;
#pragma unroll
    for(int k=0;k<8;++k){
        int i = tid + 256*k;                   // [0,2048)
        int n1 = i >> 2, ws = i & 3;
        U[ws][PX(n1)] = make_float2(xa[n1*500 + ws], xb[n1*500 + ws]);
    }
    __syncthreads();
    cplx* Uw = U[w];
    fft512_wave<false>(Uw, tab, lane);
    const int n2 = n2base + w;
    cplx* yp = Y + ((size_t)s*500 + n2)*YS;
    const float tw = -2.f*PI_F/(float)NS;
#pragma unroll 1
    for(int t=0;t<8;++t){
        int q = lane + 64*t;
        int c = colord(q);
        cplx v = Uw[PX(rev8_3(c))];
        v = crotf(v, tw*(float)(n2*c));
        yp[q] = v;
    }
}

// ---------------------------------------------------------------------------
// K2: one conjugate column pair per 2-wave block (wave = one 500-pt column,
// wave-private FFT, rolled stages).  Fused filter response; conjugate
// unpack -> filter -> repack between fwd and inv.  In-place on Y. grid=512.
// ---------------------------------------------------------------------------
__global__ void __launch_bounds__(128) kFused2(cplx* __restrict__ Y,
                                               const float* __restrict__ mmL){
    __shared__ cplx tab[500];
    __shared__ cplx U[2][U2PAD];
    __shared__ float Hr[4][500];
    __shared__ float mmS[2][64];
    __shared__ float lgf[64];
    const int tid = threadIdx.x, lane = tid & 63, w = tid >> 6;
    const int L = xcd_chunk(blockIdx.x, 512);
    const int s = L >> 8, blk = L & 255;
    cplx* yb = Y + (size_t)s*500*YS + 2*blk;
    // issue global loads FIRST; they stay in flight through tab/Hr compute
    cplx rg[8];
#pragma unroll
    for(int k=0;k<8;++k){
        int i = tid + 128*k;
        rg[k] = (i < 1000) ? yb[(i>>1)*YS + (i&1)] : make_float2(0.f, 0.f);
    }
    build_tab<500,128>(tab, tid);
    if(tid < 128) mmS[tid>>6][tid&63] = mmL[2*s*64 + tid];
    if(tid < 64)  lgf[tid] = mmL[256 + tid];
    LDS_BARRIER();                        // mmS/lgf/tab visible; vmem NOT drained
    // fused filter response (H(N-k)=H(k): only k1<=256 rows exist)
    const int nrows = (blk == 0) ? 2 : 1;
    const float invN = 1.f/(float)NS;
#pragma unroll 1
    for(int idx = tid; idx < nrows*500; idx += 128){
        int r = (idx >= 500) ? 1 : 0;
        int p = idx - 500*r;
        int k1 = (blk == 0) ? (r ? 256 : 0) : blk;
        int k2 = p2k2(p);
        int kf = k1 + 512*k2;
        int kk = min(kf, NS - kf);
        float lf = logf((float)kk*(22050.f/(float)NS) + 1e-7f);
        float wsum = 0.f, a0 = 0.f, a1 = 0.f;
#pragma unroll 8
        for(int jb=0;jb<64;++jb){
            float d = lf - lgf[jb];
            float e = __expf(-2.f*d*d);
            wsum += e; a0 += e*mmS[0][jb]; a1 += e*mmS[1][jb];
        }
        float inv = invN/(wsum + 1e-7f);
        if(r==0){ Hr[0][p] = a0*inv; Hr[1][p] = a1*inv; }
        else    { Hr[2][p] = a0*inv; Hr[3][p] = a1*inv; }
    }
    // park loads into LDS (compiler inserts the vmcnt waits here)
#pragma unroll
    for(int k=0;k<8;++k){
        int i = tid + 128*k;
        if(i < 1000) U[i&1][PX(i>>1)] = rg[k];
    }
    __syncthreads();                      // U + Hr visible to both waves
    cplx* Uw = U[w];
    fft500_wave<false>(Uw, tab, lane);
    __syncthreads();
    // ---- conjugate-pair unpack -> filter -> repack ----
    if(blk == 0){
        if(w == 0){
            // column k1=0, self-paired: partner k2' = (500-k2)%500
#pragma unroll 1
            for(int t=0;t<8;++t){
                int p = lane + 64*t;
                if(p < 500){
                    int k2 = p2k2(p);
                    int pp = k22p((500 - k2) % 500);
                    if(p <= pp){
                        cplx Z1 = U[0][PX(p)], Z2 = U[0][PX(pp)];
                        cplx zk, znk;
                        hpair(Z1, Z2, Hr[0][p], Hr[1][p], &zk, &znk);
                        U[0][PX(p)]  = zk;
                        U[0][PX(pp)] = znk;
                    }
                }
            }
        } else {
            // column k1=256, self-paired: partner position 499-p
#pragma unroll 1
            for(int t=0;t<4;++t){
                int p = lane + 64*t;
                if(p < 250){
                    cplx Z1 = U[1][PX(p)], Z2 = U[1][PX(499-p)];
                    cplx zk, znk;
                    hpair(Z1, Z2, Hr[2][p], Hr[3][p], &zk, &znk);
                    U[1][PX(p)]     = zk;
                    U[1][PX(499-p)] = znk;
                }
            }
        }
    } else {
        // cross pair: (col blk, p) <-> (col 512-blk, 499-p); wave w owns
        // p in [w*250, w*250+250) -> disjoint writes.
#pragma unroll 1
        for(int t=0;t<4;++t){
            int pl = lane + 64*t;
            if(pl < 250){
                int p = w*250 + pl;
                cplx Z1 = U[0][PX(p)], Z2 = U[1][PX(499-p)];
                cplx zk, znk;
                hpair(Z1, Z2, Hr[0][p], Hr[1][p], &zk, &znk);
                U[0][PX(p)]     = zk;
                U[1][PX(499-p)] = znk;
            }
        }
    }
    __syncthreads();
    fft500_wave<true>(Uw, tab, lane);
    __syncthreads();                      // store reads across both columns
    const float tw = 2.f*PI_F/(float)NS;
#pragma unroll 1
    for(int k=0;k<8;++k){
        int i = tid + 128*k;
        if(i < 1000){
            int n2 = i >> 1, ws = i & 1;
            int cc = colord(2*blk + ws);
            cplx v = U[ws][PX(n2)];
            v = crotf(v, tw*(float)(n2*cc));
            yb[n2*YS + ws] = v;
        }
    }
}

// ---------------------------------------------------------------------------
// K3: inverse 512-FFT; 4 n2-columns per 4-wave block (wave-per-column,
// rolled).  Re -> batch 2s, Im -> batch 2s+1.  grid = 250.
// ---------------------------------------------------------------------------
__global__ void __launch_bounds__(256) kFused3(const cplx* __restrict__ Y,
                                               float* __restrict__ out){
    __shared__ cplx tab[512];
    __shared__ cplx U[4][U1PAD];
    const int tid = threadIdx.x, lane = tid & 63, w = tid >> 6;
    const int g = xcd_chunk(blockIdx.x, 250);
    const int s = g / 125;
    const int n2base = (g - s*125) * 4;
    build_tab<512,256>(tab, tid);
    const cplx* yp = Y + ((size_t)s*500 + n2base)*YS;
#pragma unroll 1
    for(int k=0;k<8;++k){
        int i = tid + 256*k;                   // [0,2048)
        int ws = i >> 9, q = i & 511;          // coalesced in q
        cplx v = yp[(size_t)ws*YS + q];
        U[ws][PX(rev8_3(colord(q)))] = v;      // bin c -> DIT position rev8_3(c)
    }
    __syncthreads();
    cplx* Uw = U[w];
    fft512_wave<true>(Uw, tab, lane);
    __syncthreads();                           // store reads across columns
    float* oa = out + (size_t)(2*s)*NS + n2base;
    float* ob = out + (size_t)(2*s+1)*NS + n2base;
#pragma unroll 1
    for(int k=0;k<8;++k){
        int i = tid + 256*k;
        int n1 = i >> 2, ws = i & 3;
        cplx v = U[ws][PX(n1)];
        oa[n1*500 + ws] = v.x;
        ob[n1*500 + ws] = v.y;
    }
}

// ---------------------------------------------------------------------------
extern "C" void kernel_launch(void* const* d_in, const int* in_sizes, int n_in,
                              void* d_out, int out_size, void* d_ws, size_t ws_size,
                              hipStream_t stream) {
    const float* fm = (const float*)d_in[0];     // (4,500,64)
    const float* noise = (const float*)d_in[1];  // (4,256000)
    float* out = (float*)d_out;

    char* ws = (char*)d_ws;
    cplx*  Y   = (cplx*)ws;                      // 2 * 500 * 528 cplx = 4,224,000 B
    float* mmL = (float*)(ws + 4224000);         // mm[4][64] + logff[64]

    kFused1<<<255, 256, 0, stream>>>(fm, noise, mmL, Y);
    kFused2<<<512, 128, 0, stream>>>(Y, mmL);
    kFused3<<<250, 256, 0, stream>>>(Y, out);
}